// Round 7
// baseline (122.360 us; speedup 1.0000x reference)
//
#include <hip/hip_runtime.h>

// Single-kernel MFMA-tail, take 4.
// Changes vs round 6 (82.9us):
//  1) qcompose merged into the main kernel: wave 0 composes the fixed 32x32
//     real tail matrix W (split-f16 hi + lo*2048) into LDS, one __syncthreads.
//     Grid-stride (grid=1536 = 6 blocks/CU, ~2.7 chunks/block) amortizes the
//     per-block compose (~2600cyc on one wave, ~1.6us aggregate) against the
//     ~3-5us saved by dropping the serialized 1-block dispatch.
//  2) Tail GEMM now v_mfma_f32_32x32x16_f16: 8 MFMAs (was 16). D = W*S^T at
//     32x32 -> C/D layout (m74/m101-verified: col=lane&31,
//     row=(reg&3)+8*(reg>>2)+4*(lane>>5)) gives each lane re+im of 8 complex
//     dims of ONE sample -> probs lane-local, reduce = ONE shfl_xor(32) stage
//     (8 shfl, was 32). A/B k-mapping uncertainty cancels (identical
//     lane-group addressing on both operands).
//  3) Next-chunk x prefetched under the MFMA section.

using f16x8  = __attribute__((ext_vector_type(8))) _Float16;
using f32x16 = __attribute__((ext_vector_type(16))) float;

struct C { float r, i; };

__device__ __forceinline__ C cmul(C a, C b) {
    C o;
    o.r = fmaf(a.r, b.r, -(a.i * b.i));
    o.i = fmaf(a.r, b.i,   a.i * b.r);
    return o;
}

// o = u*a + w*b where u=(ur,ui), w=(wr,wi) are gate entries.
__device__ __forceinline__ C cmadd(float ur, float ui, float wr, float wi, C a, C b) {
    C o;
    o.r = fmaf(ur, a.r, fmaf(-ui, a.i, fmaf(wr, b.r, -(wi * b.i))));
    o.i = fmaf(ur, a.i, fmaf( ui, a.r, fmaf(wr, b.i,   wi * b.r)));
    return o;
}

template <int BP>
__device__ __forceinline__ void apply_gate(C st[16], float4 A4, float4 B4) {
#pragma unroll
    for (int i = 0; i < 8; i++) {
        const int lo = ((i >> BP) << (BP + 1)) | (i & ((1 << BP) - 1));
        const int hi = lo | (1 << BP);
        const C a = st[lo], b = st[hi];
        st[lo] = cmadd(A4.x, A4.y, A4.z, A4.w, a, b);
        st[hi] = cmadd(B4.x, B4.y, B4.z, B4.w, a, b);
    }
}

template <int CB, int TB>
__device__ __forceinline__ void cnot(C st[16]) {
#pragma unroll
    for (int i = 0; i < 16; i++) {
        if ((i & (1 << CB)) && !(i & (1 << TB))) {
            C t = st[i];
            st[i] = st[i | (1 << TB)];
            st[i | (1 << TB)] = t;
        }
    }
}

struct Enc { float r0, i0, r1, i1; };
// v_q = (cos(xn) e^{-i xn/2}, sin(xn) e^{+i xn/2}), xn = pi*tanh(x).
// HW v_sin/v_cos take REVOLUTIONS: sin(pi t/2) = v_sin(t/4), t in (-1,1).
__device__ __forceinline__ Enc encode(float xq) {
    const float ax = fabsf(xq);
    const float e  = __builtin_amdgcn_exp2f(ax * -2.8853900817779268f);  // exp(-2|x|)
    const float r  = __builtin_amdgcn_rcpf(1.0f + e);
    const float t  = copysignf((1.0f - e) * r, xq);                       // tanh(x)
    const float sh = __builtin_amdgcn_sinf(t * 0.25f);                    // sin(pi t/2)
    const float ch = __builtin_amdgcn_cosf(t * 0.25f);                    // cos(pi t/2)
    const float s  = 2.0f * sh * ch;                                      // sin(pi t)
    const float c  = fmaf(-2.0f * sh, sh, 1.0f);                          // cos(pi t)
    return {c * ch, -(c * sh), s * ch, s * sh};
}

// Wave-level LDS fence: orders this wave's DS ops across it (compiler memory
// clobber stops reordering - the round-4 bug; lgkmcnt(0) drains the DS queue;
// sched_barrier pins the point, rule #18 defense).
__device__ __forceinline__ void wave_lds_fence() {
    asm volatile("s_waitcnt lgkmcnt(0)" ::: "memory");
    __builtin_amdgcn_sched_barrier(0);
}

#define ROWB 80   // LDS sample-row stride: 64 B data + 16 pad (2-way banks = free)

__global__ __launch_bounds__(256, 6) void qlayer_kernel(const float* __restrict__ x,
                                                        const float* __restrict__ qw,
                                                        float* __restrict__ out,
                                                        int B, int nChunks) {
    __shared__ float4 Ug[12][2];
    __shared__ __align__(16) unsigned char Wh_lds[2048];   // f16 W hi  [32][32]
    __shared__ __align__(16) unsigned char Wl_lds[2048];   // f16 W lo  (x2048)
    __shared__ __align__(16) unsigned char slab_all[4 * 64 * ROWB];  // per-wave S

    const int tid  = threadIdx.x;
    const int lane = tid & 63;
    const int wid  = tid >> 6;

    // ---- per-block compose (wave 0) -------------------------------------
    if (tid < 12) {
        const float phi = qw[tid * 3 + 0];
        const float th  = qw[tid * 3 + 1];
        const float om  = qw[tid * 3 + 2];
        // Rot = RZ(om) RY(th) RZ(phi)
        float s, c;   __sincosf(0.5f * th, &s, &c);
        float sa, ca; __sincosf(0.5f * (phi + om), &sa, &ca);
        float sb, cb; __sincosf(0.5f * (phi - om), &sb, &cb);
        Ug[tid][0] = make_float4(c * ca, -c * sa, -s * cb, -s * sb);
        Ug[tid][1] = make_float4(s * cb, -s * sb, c * ca, c * sa);
    }
    if (tid < 16) {
        wave_lds_fence();   // Ug written by lanes 0-11, read by lanes 0-15 (same wave)
        // Push basis state e_tid through the tail: ring0, L1, ring, L2, ring.
        C st[16];
#pragma unroll
        for (int i = 0; i < 16; i++) { st[i].r = 0.0f; st[i].i = 0.0f; }
        st[tid].r = 1.0f;

        cnot<3, 2>(st); cnot<2, 1>(st); cnot<1, 0>(st); cnot<0, 3>(st);
        apply_gate<3>(st, Ug[4][0], Ug[4][1]);
        apply_gate<2>(st, Ug[5][0], Ug[5][1]);
        apply_gate<1>(st, Ug[6][0], Ug[6][1]);
        apply_gate<0>(st, Ug[7][0], Ug[7][1]);
        cnot<3, 2>(st); cnot<2, 1>(st); cnot<1, 0>(st); cnot<0, 3>(st);
        apply_gate<3>(st, Ug[8][0], Ug[8][1]);
        apply_gate<2>(st, Ug[9][0], Ug[9][1]);
        apply_gate<1>(st, Ug[10][0], Ug[10][1]);
        apply_gate<0>(st, Ug[11][0], Ug[11][1]);
        cnot<3, 2>(st); cnot<2, 1>(st); cnot<1, 0>(st); cnot<0, 3>(st);

        // W real rep: out[j] = sum_k W[j][k] in[k], j/k = 2*dim + (0:re,1:im).
        // Basis t -> columns (2t, 2t+1):
        //   row 2d: (Tr, -Ti)   row 2d+1: (Ti, Tr)
        unsigned* whiW = reinterpret_cast<unsigned*>(Wh_lds);
        unsigned* wloW = reinterpret_cast<unsigned*>(Wl_lds);
#pragma unroll
        for (int d = 0; d < 16; d++) {
            const float vr = st[d].r, vi = st[d].i;
            const _Float16 hr  = (_Float16)vr, hi_ = (_Float16)vi;
            const _Float16 lr  = (_Float16)((vr - (float)hr)  * 2048.0f);
            const _Float16 li  = (_Float16)((vi - (float)hi_) * 2048.0f);
            const unsigned uhr = (unsigned)__builtin_bit_cast(unsigned short, hr);
            const unsigned uhi = (unsigned)__builtin_bit_cast(unsigned short, hi_);
            const unsigned ulr = (unsigned)__builtin_bit_cast(unsigned short, lr);
            const unsigned uli = (unsigned)__builtin_bit_cast(unsigned short, li);
            whiW[(2 * d) * 16 + tid]     = uhr | ((uhi ^ 0x8000u) << 16);
            whiW[(2 * d + 1) * 16 + tid] = uhi | (uhr << 16);
            wloW[(2 * d) * 16 + tid]     = ulr | ((uli ^ 0x8000u) << 16);
            wloW[(2 * d + 1) * 16 + tid] = uli | (ulr << 16);
        }
    }
    __syncthreads();

    // ---- persistent fragments -------------------------------------------
    // A-operand (W): row j = lane&31, k-chunk 8*(lane>>5)+j' of k-step s.
    const int j32 = lane & 31;
    const int h   = lane >> 5;
    const f16x8 Wh0 = *reinterpret_cast<const f16x8*>(Wh_lds + j32 * 64 + h * 16);
    const f16x8 Wh1 = *reinterpret_cast<const f16x8*>(Wh_lds + j32 * 64 + 32 + h * 16);
    const f16x8 Wl0 = *reinterpret_cast<const f16x8*>(Wl_lds + j32 * 64 + h * 16);
    const f16x8 Wl1 = *reinterpret_cast<const f16x8*>(Wl_lds + j32 * 64 + 32 + h * 16);

    char* slab  = reinterpret_cast<char*>(slab_all) + wid * (64 * ROWB);
    char* myrow = slab + lane * ROWB;
    const float4* x4 = reinterpret_cast<const float4*>(x);

    int chunk = blockIdx.x;
    if (chunk >= nChunks) return;
    int b = chunk * 256 + tid;
    float4 xv = x4[b < B ? b : (B - 1)];

    while (true) {
        const float xs[4] = {xv.x, xv.y, xv.z, xv.w};

        // Front end: encode + merge layer-0 Rot (product state).
        C v[4][2];
#pragma unroll
        for (int q = 0; q < 4; q++) {
            const Enc e = encode(xs[q]);
            const C a{e.r0, e.i0}, bv{e.r1, e.i1};
            const float4 A4 = Ug[q][0], B4 = Ug[q][1];
            v[q][0] = cmadd(A4.x, A4.y, A4.z, A4.w, a, bv);
            v[q][1] = cmadd(B4.x, B4.y, B4.z, B4.w, a, bv);
        }

        // Outer product fused with hi-f16 pack.
        C t01[4], t23[4];
#pragma unroll
        for (int i = 0; i < 4; i++) {
            t01[i] = cmul(v[0][(i >> 1) & 1], v[1][i & 1]);
            t23[i] = cmul(v[2][(i >> 1) & 1], v[3][i & 1]);
        }
        f16x8 vh[4];
#pragma unroll
        for (int i = 0; i < 16; i++) {
            const C s = cmul(t01[i >> 2], t23[i & 3]);
            vh[i >> 2][2 * (i & 3)]     = (_Float16)s.r;
            vh[i >> 2][2 * (i & 3) + 1] = (_Float16)s.i;
        }
        wave_lds_fence();   // prior chunk's S reads complete before overwrite
#pragma unroll
        for (int c = 0; c < 4; c++)
            *reinterpret_cast<f16x8*>(myrow + c * 16) = vh[c];

        // Prefetch next chunk's x (hidden under the MFMA section).
        const int nextChunk = chunk + gridDim.x;
        const bool more = nextChunk < nChunks;
        int bn = 0; float4 xn;
        if (more) {
            bn = nextChunk * 256 + tid;
            xn = x4[bn < B ? bn : (B - 1)];
        }

        wave_lds_fence();   // pack visible before cross-lane S reads

        // Tail: D = W * S^T, 32x32x16, 2 k-steps, 2 sample-tiles of 32.
        // Lane owns sample col = lane&31 of each tile; own tile = h.
        float r3[2], r2[2], r1[2], r0[2];
#pragma unroll
        for (int n = 0; n < 2; n++) {
            const char* srow = slab + (32 * n + j32) * ROWB + h * 16;
            const f16x8 S0 = *reinterpret_cast<const f16x8*>(srow);
            const f16x8 S1 = *reinterpret_cast<const f16x8*>(srow + 32);
            const f32x16 Z = {0.f,0.f,0.f,0.f,0.f,0.f,0.f,0.f,
                              0.f,0.f,0.f,0.f,0.f,0.f,0.f,0.f};
            f32x16 D = __builtin_amdgcn_mfma_f32_32x32x16_f16(Wh0, S0, Z, 0, 0, 0);
            D        = __builtin_amdgcn_mfma_f32_32x32x16_f16(Wh1, S1, D, 0, 0, 0);
            f32x16 L = __builtin_amdgcn_mfma_f32_32x32x16_f16(Wl0, S0, Z, 0, 0, 0);
            L        = __builtin_amdgcn_mfma_f32_32x32x16_f16(Wl1, S1, L, 0, 0, 0);

            // reg r: row = (r&3)+8*(r>>2)+4h; pairs (2m,2m+1) = (re,im) of
            // d(m) = 4*(m>>1) + 2h + (m&1).
            float p[8];
#pragma unroll
            for (int m = 0; m < 8; m++) {
                const float c0 = fmaf(L[2 * m],     4.8828125e-4f, D[2 * m]);
                const float c1 = fmaf(L[2 * m + 1], 4.8828125e-4f, D[2 * m + 1]);
                p[m] = fmaf(c1, c1, c0 * c0);
            }
            const float e67 = p[6] + p[7];
            float t3 = (p[4] + p[5]) + e67;                    // d&8: m=4..7
            float t2 = (p[2] + p[3]) + e67;                    // d&4: m=2,3,6,7
            float t0 = (p[1] + p[3]) + (p[5] + p[7]);          // d&1: m odd
            const float tAll = ((p[0] + p[2]) + (p[4] + p[6])) + t0;
            float t1 = h ? tAll : 0.0f;                        // d&2 <=> h
            t3 += __shfl_xor(t3, 32); t2 += __shfl_xor(t2, 32);
            t1 += __shfl_xor(t1, 32); t0 += __shfl_xor(t0, 32);
            r3[n] = t3; r2[n] = t2; r1[n] = t1; r0[n] = t0;
        }
        const float e3 = h ? r3[1] : r3[0];
        const float e2 = h ? r2[1] : r2[0];
        const float e1 = h ? r1[1] : r1[0];
        const float e0 = h ? r0[1] : r0[0];

        if (b < B) {
            float4 ev;
            ev.x = fmaf(-2.0f, e3, 1.0f);
            ev.y = fmaf(-2.0f, e2, 1.0f);
            ev.z = fmaf(-2.0f, e1, 1.0f);
            ev.w = fmaf(-2.0f, e0, 1.0f);
            reinterpret_cast<float4*>(out)[b] = ev;
        }

        if (!more) break;
        chunk = nextChunk; b = bn; xv = xn;
    }
}

extern "C" void kernel_launch(void* const* d_in, const int* in_sizes, int n_in,
                              void* d_out, int out_size, void* d_ws, size_t ws_size,
                              hipStream_t stream) {
    const float* x  = (const float*)d_in[0];
    const float* qw = (const float*)d_in[1];
    float* out = (float*)d_out;
    const int B = in_sizes[0] / 4;
    const int nChunks = (B + 255) / 256;
    const int grid = nChunks < 1536 ? nChunks : 1536;   // 6 blocks/CU, grid-stride
    qlayer_kernel<<<grid, 256, 0, stream>>>(x, qw, out, B, nChunks);
}